// Round 8
// baseline (145.135 us; speedup 1.0000x reference)
//
#include <hip/hip_runtime.h>
#include <hip/hip_bf16.h>
#include <cmath>

// Problem constants (fixed by reference)
#define NB   4      // batch
#define LQ   2048   // query len
#define SK   2048   // source len
#define DD   256    // in depth
#define HD   256    // hidden
#define FC   8      // heads
#define CH   32     // channels per head (HD/FC)
#define MHEAD 32    // NB*FC

// hh-filter margin: |f32dot - bf16dot| <= 2*2^-9 per side (unit rows) + slack
#define MARGIN 0.0085f
#define CAP    12   // candidate slots per row (avg ~1.2 needed)

typedef float f32x16 __attribute__((ext_vector_type(16)));
typedef float f32x2  __attribute__((ext_vector_type(2)));
typedef short bf16x8 __attribute__((ext_vector_type(8)));
typedef unsigned short ushort8v __attribute__((ext_vector_type(8)));

__device__ inline unsigned short f32_to_bf16_bits(float v) {
    __hip_bfloat16 b = __float2bfloat16(v);   // round-to-nearest
    return __builtin_bit_cast(unsigned short, b);
}
__device__ inline unsigned int ord_encode(float v) {
    unsigned int u = __float_as_uint(v);
    return (u & 0x80000000u) ? ~u : (u | 0x80000000u);
}
__device__ inline float ord_decode(unsigned int e) {
    unsigned int u = (e & 0x80000000u) ? (e & 0x7fffffffu) : ~e;
    return __uint_as_float(u);
}

#define MFMA32(a, b, c) __builtin_amdgcn_mfma_f32_32x32x16_bf16(a, b, c, 0, 0, 0)

// ------------------------------------------------------------------
// Merged projection GEMM (K1+K2). 128x64 tile, 8x4/thread, LDS dbuf.
// Grid: dim3(12, 64). nt 0..3 -> x0@W0+b0; nt 4..11 -> x1@W1+b1.
// Per-acc-element FMA chain is k-ascending -> bit-identical to the
// passing R2/R7 kernels (argmax path must stay bit-stable).
// f32 FMA floor for 3.2 GFLOP = 20.4 us; this cuts staging/barrier
// overhead per FLOP by 2x vs the 64x64 tile.
// ------------------------------------------------------------------
__global__ __launch_bounds__(256)
void proj_gemm_kernel(const float* __restrict__ x0, const float* __restrict__ x1,
                      const float* __restrict__ W0, const float* __restrict__ b0f,
                      const float* __restrict__ W1, const float* __restrict__ b1f,
                      float* __restrict__ xq, float* __restrict__ xk,
                      float* __restrict__ xv)
{
    __shared__ float As[2][16][132];   // [k][m], 132 = 128+4 pad
    __shared__ float Bs[2][16][64];    // [k][n]
    const int nt  = blockIdx.x;        // 0..11 (wave-uniform branch)
    const bool is0 = (nt < 4);
    const float* A    = is0 ? x0 : x1;
    const float* B    = is0 ? W0 : W1;
    const float* bias = is0 ? b0f : b1f;
    const int N  = is0 ? HD : 2 * HD;
    const int bn = (is0 ? nt : nt - 4) * 64;
    const int bm = blockIdx.y * 128;
    const int K  = DD;

    const int tx = threadIdx.x & 15;
    const int ty = threadIdx.x >> 4;
    f32x2 acc2[8][2] = {};

    const int arow = threadIdx.x >> 1;           // 0..127
    const int akq  = (threadIdx.x & 1) << 3;     // 0 or 8
    const int bkr  = threadIdx.x >> 4;           // 0..15
    const int bnq  = (threadIdx.x & 15) << 2;    // 0..60

    // prologue: stage chunk 0
    {
        const float4 a4 = *(const float4*)&A[(size_t)(bm + arow) * K + akq];
        const float4 a5 = *(const float4*)&A[(size_t)(bm + arow) * K + akq + 4];
        const float4 b4 = *(const float4*)&B[(size_t)bkr * N + bn + bnq];
        As[0][akq + 0][arow] = a4.x;
        As[0][akq + 1][arow] = a4.y;
        As[0][akq + 2][arow] = a4.z;
        As[0][akq + 3][arow] = a4.w;
        As[0][akq + 4][arow] = a5.x;
        As[0][akq + 5][arow] = a5.y;
        As[0][akq + 6][arow] = a5.z;
        As[0][akq + 7][arow] = a5.w;
        *(float4*)&Bs[0][bkr][bnq] = b4;
    }
    __syncthreads();

    const int nchunk = K >> 4;   // 16
    float4 pa0, pa1, pb;
    for (int c = 0; c < nchunk; ++c) {
        const int cur = c & 1;
        if (c + 1 < nchunk) {
            const int k0 = (c + 1) << 4;
            pa0 = *(const float4*)&A[(size_t)(bm + arow) * K + k0 + akq];
            pa1 = *(const float4*)&A[(size_t)(bm + arow) * K + k0 + akq + 4];
            pb  = *(const float4*)&B[(size_t)(k0 + bkr) * N + bn + bnq];
        }
        #pragma unroll
        for (int kk = 0; kk < 16; ++kk) {
            const float4 a0 = *(const float4*)&As[cur][kk][ty << 3];
            const float4 a1 = *(const float4*)&As[cur][kk][(ty << 3) + 4];
            const f32x2 b01 = *(const f32x2*)&Bs[cur][kk][tx << 2];
            const f32x2 b23 = *(const f32x2*)&Bs[cur][kk][(tx << 2) + 2];
            const float av[8] = {a0.x, a0.y, a0.z, a0.w, a1.x, a1.y, a1.z, a1.w};
            #pragma unroll
            for (int i = 0; i < 8; ++i) {
                const f32x2 aa = {av[i], av[i]};
                acc2[i][0] = __builtin_elementwise_fma(aa, b01, acc2[i][0]);
                acc2[i][1] = __builtin_elementwise_fma(aa, b23, acc2[i][1]);
            }
        }
        if (c + 1 < nchunk) {
            const int nxt = cur ^ 1;
            As[nxt][akq + 0][arow] = pa0.x;
            As[nxt][akq + 1][arow] = pa0.y;
            As[nxt][akq + 2][arow] = pa0.z;
            As[nxt][akq + 3][arow] = pa0.w;
            As[nxt][akq + 4][arow] = pa1.x;
            As[nxt][akq + 5][arow] = pa1.y;
            As[nxt][akq + 6][arow] = pa1.z;
            As[nxt][akq + 7][arow] = pa1.w;
            *(float4*)&Bs[nxt][bkr][bnq] = pb;
        }
        __syncthreads();
    }

    #pragma unroll
    for (int i = 0; i < 8; ++i) {
        const int row = bm + (ty << 3) + i;
        #pragma unroll
        for (int j = 0; j < 4; ++j) {
            const int col = bn + (tx << 2) + j;
            const float v = acc2[i][j >> 1][j & 1] + bias[col];
            if (is0) {
                const int n = row >> 11, l = row & 2047;
                const int f = col >> 5,  cc = col & 31;
                xq[((((size_t)n * FC + f) * LQ) + l) * CH + cc] = v;
            } else {
                const int n = row >> 11, s = row & 2047;
                const int f = col >> 6,  c64 = col & 63;
                float* dst = (c64 < CH) ? xk : xv;
                dst[((((size_t)n * FC + f) * SK) + s) * CH + (c64 & 31)] = v;
            }
        }
    }
}

// ------------------------------------------------------------------
// Combined: L2-normalize q rows (sign(alpha) folded) AND k rows, in
// place (arithmetic bit-identical to R2), emit bf16 hi copies, and
// zero-init maxhh_u/cnt (replaces in-graph memsets: ~43us each).
// ------------------------------------------------------------------
__global__ __launch_bounds__(256)
void norm_split_init_kernel(float* __restrict__ xq, unsigned short* __restrict__ qhi,
                            float* __restrict__ xk, unsigned short* __restrict__ khi,
                            const float* __restrict__ alpha,
                            unsigned int* __restrict__ maxhh_u, int* __restrict__ cnt)
{
    int r = blockIdx.x * blockDim.x + threadIdx.x;
    float* p;
    unsigned short* dhi;
    float sgn = 1.f;
    if (r < MHEAD * LQ) {
        maxhh_u[r] = 0u;      // ord_encode lower bound (0 < any encoded float)
        cnt[r] = 0;
        p   = xq + (size_t)r * CH;
        dhi = qhi + (size_t)r * CH;
        if (alpha[0] < 0.f) sgn = -1.f;
    } else {
        r -= MHEAD * LQ;
        p   = xk + (size_t)r * CH;
        dhi = khi + (size_t)r * CH;
    }

    float4 v[8];
    float ss = 0.f;
    #pragma unroll
    for (int i = 0; i < 8; ++i) {
        v[i] = *(const float4*)(p + i * 4);
        ss = fmaf(v[i].x, v[i].x, ss);
        ss = fmaf(v[i].y, v[i].y, ss);
        ss = fmaf(v[i].z, v[i].z, ss);
        ss = fmaf(v[i].w, v[i].w, ss);
    }
    const float inv = sgn / fmaxf(sqrtf(ss), 1e-12f);

    ushort8v hb[4];
    #pragma unroll
    for (int i = 0; i < 8; ++i) {
        float4 w;
        w.x = v[i].x * inv; w.y = v[i].y * inv;
        w.z = v[i].z * inv; w.w = v[i].w * inv;
        *(float4*)(p + i * 4) = w;
        hb[i >> 1][(i & 1) * 4 + 0] = f32_to_bf16_bits(w.x);
        hb[i >> 1][(i & 1) * 4 + 1] = f32_to_bf16_bits(w.y);
        hb[i >> 1][(i & 1) * 4 + 2] = f32_to_bf16_bits(w.z);
        hb[i >> 1][(i & 1) * 4 + 3] = f32_to_bf16_bits(w.w);
    }
    #pragma unroll
    for (int i = 0; i < 4; ++i)
        *(ushort8v*)(dhi + i * 8) = hb[i];
}

// ------------------------------------------------------------------
// Pass A1: bf16 MFMA scan, per-row hh max via ordered-uint atomicMax.
// Grid: 32 heads * 16 qb * 4 s-chunks = 2048 blocks, 4 waves.
// v_max3_f32 folds both tiles' maxes (16 ops vs 32).
// ------------------------------------------------------------------
__global__ __launch_bounds__(256, 4)
void maxpass_kernel(const unsigned short* __restrict__ qhi,
                    const unsigned short* __restrict__ khi,
                    unsigned int* __restrict__ maxhh_u)
{
    const int b    = blockIdx.x;
    const int sc   = b & 3;
    const int qb   = (b >> 2) & 15;
    const int h    = b >> 6;
    const int wave = threadIdx.x >> 6;
    const int lane = threadIdx.x & 63;
    const int qbase = qb * 128 + wave * 32;
    const int col   = lane & 31;
    const int g8    = (lane >> 5) * 8;

    const size_t qoff = ((size_t)h * LQ + qbase + col) * CH + g8;
    const bf16x8 ah0 = *(const bf16x8*)(qhi + qoff);
    const bf16x8 ah1 = *(const bf16x8*)(qhi + qoff + 16);

    const unsigned short* kh = khi + ((size_t)h * SK + sc * 512) * CH;
    const size_t koff = (size_t)col * CH + g8;

    float maxv[16];
    #pragma unroll
    for (int r = 0; r < 16; ++r) maxv[r] = -INFINITY;

    bf16x8 t0a = *(const bf16x8*)(kh + koff);
    bf16x8 t0b = *(const bf16x8*)(kh + koff + 16);
    bf16x8 t1a = *(const bf16x8*)(kh + koff + 32 * CH);
    bf16x8 t1b = *(const bf16x8*)(kh + koff + 32 * CH + 16);

    for (int sb = 0; sb < 16; sb += 2) {
        const bf16x8 c0a = t0a, c0b = t0b, c1a = t1a, c1b = t1b;
        if (sb + 2 < 16) {
            const size_t o = koff + (size_t)(sb + 2) * 32 * CH;
            t0a = *(const bf16x8*)(kh + o);
            t0b = *(const bf16x8*)(kh + o + 16);
            t1a = *(const bf16x8*)(kh + o + 32 * CH);
            t1b = *(const bf16x8*)(kh + o + 32 * CH + 16);
        }
        f32x16 c = {0.f, 0.f, 0.f, 0.f, 0.f, 0.f, 0.f, 0.f,
                    0.f, 0.f, 0.f, 0.f, 0.f, 0.f, 0.f, 0.f};
        c = MFMA32(ah0, c0a, c);
        c = MFMA32(ah1, c0b, c);
        f32x16 d = {0.f, 0.f, 0.f, 0.f, 0.f, 0.f, 0.f, 0.f,
                    0.f, 0.f, 0.f, 0.f, 0.f, 0.f, 0.f, 0.f};
        d = MFMA32(ah0, c1a, d);
        d = MFMA32(ah1, c1b, d);
        #pragma unroll
        for (int r = 0; r < 16; ++r)
            maxv[r] = fmaxf(maxv[r], fmaxf(c[r], d[r]));   // -> v_max3_f32
    }

    #pragma unroll
    for (int r = 0; r < 16; ++r) {
        float v = maxv[r];
        #pragma unroll
        for (int m = 16; m >= 1; m >>= 1)
            v = fmaxf(v, __shfl_xor(v, m, 64));
        maxv[r] = v;
    }
    if (col == 0) {
        const int rbase = h * LQ + qbase + 4 * (lane >> 5);
        #pragma unroll
        for (int r = 0; r < 16; ++r)
            atomicMax(&maxhh_u[rbase + (r & 3) + 8 * (r >> 2)], ord_encode(maxv[r]));
    }
}

// ------------------------------------------------------------------
// Pass A2: identical MFMA scan; append s with hh >= max-MARGIN.
// Fast path builds a per-lane 16-bit hit mask (cmp+cndmask, no
// branches); rare slow path re-runs the exact per-value tests.
// fmax is exact, so mask bit r set <=> (c[r]>=thr[r] || d[r]>=thr[r]).
// ------------------------------------------------------------------
__global__ __launch_bounds__(256, 4)
void candpass_kernel(const unsigned short* __restrict__ qhi,
                     const unsigned short* __restrict__ khi,
                     const unsigned int* __restrict__ maxhh_u,
                     int* __restrict__ cnt, int* __restrict__ cand)
{
    const int b    = blockIdx.x;
    const int sc   = b & 3;
    const int qb   = (b >> 2) & 15;
    const int h    = b >> 6;
    const int wave = threadIdx.x >> 6;
    const int lane = threadIdx.x & 63;
    const int qbase = qb * 128 + wave * 32;
    const int col   = lane & 31;
    const int g8    = (lane >> 5) * 8;

    const size_t qoff = ((size_t)h * LQ + qbase + col) * CH + g8;
    const bf16x8 ah0 = *(const bf16x8*)(qhi + qoff);
    const bf16x8 ah1 = *(const bf16x8*)(qhi + qoff + 16);

    int   rows[16];
    float thr[16];
    {
        const int rbase = h * LQ + qbase + 4 * (lane >> 5);
        #pragma unroll
        for (int r = 0; r < 16; ++r) {
            rows[r] = rbase + (r & 3) + 8 * (r >> 2);
            thr[r]  = ord_decode(maxhh_u[rows[r]]) - MARGIN;
        }
    }

    const unsigned short* kh = khi + ((size_t)h * SK + sc * 512) * CH;
    const size_t koff = (size_t)col * CH + g8;
    const int sbase = sc * 512;

    bf16x8 t0a = *(const bf16x8*)(kh + koff);
    bf16x8 t0b = *(const bf16x8*)(kh + koff + 16);
    bf16x8 t1a = *(const bf16x8*)(kh + koff + 32 * CH);
    bf16x8 t1b = *(const bf16x8*)(kh + koff + 32 * CH + 16);

    for (int sb = 0; sb < 16; sb += 2) {
        const bf16x8 c0a = t0a, c0b = t0b, c1a = t1a, c1b = t1b;
        if (sb + 2 < 16) {
            const size_t o = koff + (size_t)(sb + 2) * 32 * CH;
            t0a = *(const bf16x8*)(kh + o);
            t0b = *(const bf16x8*)(kh + o + 16);
            t1a = *(const bf16x8*)(kh + o + 32 * CH);
            t1b = *(const bf16x8*)(kh + o + 32 * CH + 16);
        }
        f32x16 c = {0.f, 0.f, 0.f, 0.f, 0.f, 0.f, 0.f, 0.f,
                    0.f, 0.f, 0.f, 0.f, 0.f, 0.f, 0.f, 0.f};
        c = MFMA32(ah0, c0a, c);
        c = MFMA32(ah1, c0b, c);
        f32x16 d = {0.f, 0.f, 0.f, 0.f, 0.f, 0.f, 0.f, 0.f,
                    0.f, 0.f, 0.f, 0.f, 0.f, 0.f, 0.f, 0.f};
        d = MFMA32(ah0, c1a, d);
        d = MFMA32(ah1, c1b, d);

        unsigned int hit = 0u;
        #pragma unroll
        for (int r = 0; r < 16; ++r) {
            const float e = fmaxf(c[r], d[r]);
            hit = (e >= thr[r]) ? (hit | (1u << r)) : hit;
        }
        if (hit) {
            const int s0 = sbase + sb * 32 + col;
            #pragma unroll
            for (int r = 0; r < 16; ++r) {
                if (hit & (1u << r)) {
                    if (c[r] >= thr[r]) {
                        const int slot = atomicAdd(&cnt[rows[r]], 1);
                        if (slot < CAP) cand[(size_t)rows[r] * CAP + slot] = s0;
                    }
                    if (d[r] >= thr[r]) {
                        const int slot = atomicAdd(&cnt[rows[r]], 1);
                        if (slot < CAP) cand[(size_t)rows[r] * CAP + slot] = s0 + 32;
                    }
                }
            }
        }
    }
}

// ------------------------------------------------------------------
// Pass B: exact f32 refine (chain bit-identical to R2) + sigmoid +
// gather + scale; writes new_x0 as bf16 for the MFMA output GEMM.
// ------------------------------------------------------------------
__global__ __launch_bounds__(256)
void refine_gather_kernel(const float* __restrict__ qn,
                          const float* __restrict__ kn,
                          const int* __restrict__ cnt, const int* __restrict__ cand,
                          const float* __restrict__ xv,
                          const float* __restrict__ alpha, const float* __restrict__ beta,
                          unsigned short* __restrict__ nxb)  // (4,2048,256) bf16
{
    const int r = blockIdx.x * blockDim.x + threadIdx.x;  // h*2048 + l
    const int h = r >> 11, l = r & 2047;

    float qr[CH];
    #pragma unroll
    for (int i = 0; i < 8; ++i) {
        const float4 v = *(const float4*)(qn + (size_t)r * CH + i * 4);
        qr[i * 4 + 0] = v.x; qr[i * 4 + 1] = v.y;
        qr[i * 4 + 2] = v.z; qr[i * 4 + 3] = v.w;
    }

    int m = cnt[r];
    if (m > CAP) m = CAP;
    float best = -INFINITY;
    int   bidx = 0x7fffffff;
    for (int j = 0; j < m; ++j) {
        const int s = cand[(size_t)r * CAP + j];
        const float4* k4 = (const float4*)(kn + ((size_t)h * SK + s) * CH);
        float p = 0.f;
        #pragma unroll
        for (int c = 0; c < 8; ++c) {
            const float4 kv = k4[c];
            p = fmaf(qr[c * 4 + 0], kv.x, p);
            p = fmaf(qr[c * 4 + 1], kv.y, p);
            p = fmaf(qr[c * 4 + 2], kv.z, p);
            p = fmaf(qr[c * 4 + 3], kv.w, p);
        }
        if (p > best || (p == best && s < bidx)) { best = p; bidx = s; }
    }
    if (bidx == 0x7fffffff) bidx = 0;   // unreachable guard

    const float a = alpha[0], be = beta[0];
    float tv;
    int idx = bidx;
    if (a == 0.f) { idx = 0; tv = be; }
    else          { tv = fmaf(fabsf(a), best, be); }
    float val;
    if (tv >= 0.f) val = 1.f / (1.f + expf(-tv));
    else           { const float e = expf(tv); val = e / (1.f + e); }

    const float4* vr = (const float4*)(xv + ((size_t)h * SK + idx) * CH);
    const int n = h >> 3, f = h & 7;
    unsigned short* out = nxb + (((size_t)n * LQ + l) * (FC * CH)) + f * CH;
    #pragma unroll
    for (int i = 0; i < 8; ++i) {
        const float4 w = vr[i];
        ushort8v o;
        o[0] = f32_to_bf16_bits(w.x * val);
        o[1] = f32_to_bf16_bits(w.y * val);
        o[2] = f32_to_bf16_bits(w.z * val);
        o[3] = f32_to_bf16_bits(w.w * val);
        *(unsigned long long*)(out + i * 4) = __builtin_bit_cast(unsigned long long,
            *(const ulong1*)&o);
    }
}

// ------------------------------------------------------------------
// Wm (256x256 f32, row-major [k][n]) -> bf16 swizzled B-frag layout:
// wm_s[(k>>4)*4096 + n*16 + (k&15)]
// ------------------------------------------------------------------
__global__ __launch_bounds__(256)
void wmprep_kernel(const float* __restrict__ Wm, unsigned short* __restrict__ wm_s)
{
    const int i = blockIdx.x * 256 + threadIdx.x;   // 0..65535
    const int k = i >> 8, n = i & 255;
    wm_s[(k >> 4) * 4096 + n * 16 + (k & 15)] = f32_to_bf16_bits(Wm[k * 256 + n]);
}

// ------------------------------------------------------------------
// K6: out = nx(bf16) @ Wm(bf16 swizzled) + bm, f32 out. MFMA 32x32 tiles.
// ------------------------------------------------------------------
__global__ __launch_bounds__(256)
void gemm_out_mfma_kernel(const unsigned short* __restrict__ nxb,
                          const unsigned short* __restrict__ wm_s,
                          const float* __restrict__ bm, float* __restrict__ out)
{
    const int wave = threadIdx.x >> 6;
    const int lane = threadIdx.x & 63;
    const int idx  = blockIdx.x * 4 + wave;
    const int mt   = idx >> 3;
    const int nt   = idx & 7;
    const int col  = lane & 31;
    const int g8   = (lane >> 5) * 8;

    const unsigned short* aptr = nxb + (size_t)(mt * 32 + col) * 256 + g8;
    const unsigned short* bptr = wm_s + nt * 32 * 16 + col * 16 + g8;

    f32x16 acc = {0.f, 0.f, 0.f, 0.f, 0.f, 0.f, 0.f, 0.f,
                  0.f, 0.f, 0.f, 0.f, 0.f, 0.f, 0.f, 0.f};
    #pragma unroll 4
    for (int kc = 0; kc < 16; ++kc) {
        const bf16x8 a = *(const bf16x8*)(aptr + kc * 16);
        const bf16x8 bfr = *(const bf16x8*)(bptr + (size_t)kc * 4096);
        acc = MFMA32(a, bfr, acc);
    }

    const int n0 = nt * 32;
    const float bias = bm[n0 + col];
    #pragma unroll
    for (int r = 0; r < 16; ++r) {
        const int row = mt * 32 + (r & 3) + 8 * (r >> 2) + 4 * (lane >> 5);
        out[(size_t)row * 256 + n0 + col] = acc[r] + bias;
    }
}

// ------------------------------------------------------------------
extern "C" void kernel_launch(void* const* d_in, const int* in_sizes, int n_in,
                              void* d_out, int out_size, void* d_ws, size_t ws_size,
                              hipStream_t stream)
{
    const float* x0 = (const float*)d_in[0];
    const float* x1 = (const float*)d_in[1];
    const float* W0 = (const float*)d_in[2];
    const float* b0 = (const float*)d_in[3];
    const float* W1 = (const float*)d_in[4];
    const float* b1 = (const float*)d_in[5];
    const float* Wm = (const float*)d_in[6];
    const float* bm = (const float*)d_in[7];
    const float* alpha = (const float*)d_in[8];
    const float* beta  = (const float*)d_in[9];
    float* out = (float*)d_out;

    char* ws = (char*)d_ws;
    const size_t MB = 1024ull * 1024ull;
    float* x0q = (float*)(ws + 0);          // (32,2048,32) f32, normalized in place
    float* x1k = (float*)(ws + 8 * MB);     // (32,2048,32) f32, normalized in place
    float* x1v = (float*)(ws + 16 * MB);    // (32,2048,32) f32 values
    unsigned short* qhi = (unsigned short*)(ws + 24 * MB);  // 4MB (dead after A2)
    unsigned short* khi = (unsigned short*)(ws + 28 * MB);  // 4MB
    unsigned int* maxhh_u = (unsigned int*)(ws + 32 * MB);            // 256KB
    int* cnt  = (int*)(ws + 32 * MB + 256 * 1024);                    // 256KB
    int* cand = (int*)(ws + 32 * MB + 512 * 1024);                    // 3MB
    unsigned short* wm_s = (unsigned short*)(ws + 32 * MB + 3584 * 1024); // 128KB
    unsigned short* nxb  = (unsigned short*)(ws + 24 * MB); // reuse qhi region

    const int Mrows = NB * LQ;   // 8192

    // K1+K2 merged: projections, 128x64 tile, 768 blocks (3/CU exact)
    proj_gemm_kernel<<<dim3(12, Mrows / 128), 256, 0, stream>>>(
        x0, x1, W0, b0, W1, b1, x0q, x1k, x1v);
    // Wm bf16 swizzle (independent)
    wmprep_kernel<<<256, 256, 0, stream>>>(Wm, wm_s);
    // K3: normalize q+k in place + bf16 hi copies + zero-init maxhh/cnt
    norm_split_init_kernel<<<(2 * MHEAD * LQ) / 256, 256, 0, stream>>>(
        x0q, qhi, x1k, khi, alpha, maxhh_u, cnt);
    // A1: MFMA hh max per row (s-split x4, atomicMax merge)
    maxpass_kernel<<<2048, 256, 0, stream>>>(qhi, khi, maxhh_u);
    // A2: MFMA hh candidate collection (s-split x4)
    candpass_kernel<<<2048, 256, 0, stream>>>(qhi, khi, maxhh_u, cnt, cand);
    // B: exact refine + sigmoid + gather + scale -> bf16 nx
    refine_gather_kernel<<<(MHEAD * LQ) / 256, 256, 0, stream>>>(
        x0q, x1k, cnt, cand, x1v, alpha, beta, nxb);
    // K6: out = nx @ Wm + bm via bf16 MFMA
    gemm_out_mfma_kernel<<<512, 256, 0, stream>>>(nxb, wm_s, bm, out);
}